// Round 13
// baseline (152.779 us; speedup 1.0000x reference)
//
#include <hip/hip_runtime.h>
#include <hip/hip_bf16.h>
#include <hip/hip_fp16.h>

#define IN_FT  128
#define OUT_FT 32
#define APITCH 136   // f16 pitch for A tile: 272B rows, benign b128 bank pattern

#define RPB   128    // rows per bucket (bucket = row >> 7)
#define NBMAX 1024   // bucket-counter array size (782 used)
#define CAP   4096   // ebin slots per bucket (mean 2048, ~45 sigma headroom)
#define BA_T  1024   // threads for binA
#define ACC_T 512    // threads for acc
#define BIN_E 16384  // binA edges per block (16/thread)
#define GT    512    // gemm threads (8 waves, 128-row tile)

typedef _Float16 f16x8 __attribute__((ext_vector_type(8)));
typedef __attribute__((ext_vector_type(4))) float f32x4;

union H2 { unsigned u; _Float16 h[2]; };

// ---- K1: swizzled f16 weight table (8 KB) + zero bucket counters ----
// wtab[tile][kt][lane][j] = w[kt*32 + (lane>>4)*8 + j][(lane&15) + tile*16]
__global__ __launch_bounds__(256) void gcn_swz(const float* __restrict__ w,
                                               _Float16* __restrict__ wtab,
                                               int* __restrict__ bptr) {
    int t = threadIdx.x;
    bptr[t]       = 0;
    bptr[t + 256] = 0;
    bptr[t + 512] = 0;
    bptr[t + 768] = 0;
    for (int i = t; i < 2 * 4 * 64 * 8; i += 256) {
        int j    = i & 7;
        int lane = (i >> 3) & 63;
        int kt   = (i >> 9) & 3;
        int tile = i >> 11;
        int k    = kt * 32 + (lane >> 4) * 8 + j;
        int c    = (lane & 15) + tile * 16;
        wtab[i] = (_Float16)w[k * OUT_FT + c];
    }
}

// ---- K2: sup(f16) = seq @ w via MFMA, 128-row tile / 8 waves / 512 thr ----
// Halves block count (782) and barriers vs the 64-row form; 34 KB LDS ->
// 4 blocks/CU (thread-limited) = full occupancy.
__global__ __launch_bounds__(GT) void gcn_gemm_mfma(const float* __restrict__ seq,
                                                    const _Float16* __restrict__ wtab,
                                                    unsigned short* __restrict__ sup,
                                                    int n) {
    __shared__ __align__(16) _Float16 at[128 * APITCH];  // 34 KB
    const int t    = threadIdx.x;
    const int base = blockIdx.x * 128;

    // stage A tile: 128 rows x 128 f32 -> f16, coalesced global reads.
    // 2048 units of (row_l, c); 512 thr -> 4 iters.
    for (int it = 0; it < 4; ++it) {
        int i     = it * GT + t;
        int row_l = i >> 4;
        int c     = i & 15;
        int row   = base + row_l;
        f16x8 v = (f16x8)0;
        if (row < n) {
            const float4* p = (const float4*)(seq + (size_t)row * IN_FT + c * 8);
            float4 lo = p[0], hi = p[1];
            v[0] = (_Float16)lo.x; v[1] = (_Float16)lo.y;
            v[2] = (_Float16)lo.z; v[3] = (_Float16)lo.w;
            v[4] = (_Float16)hi.x; v[5] = (_Float16)hi.y;
            v[6] = (_Float16)hi.z; v[7] = (_Float16)hi.w;
        }
        *(f16x8*)&at[row_l * APITCH + c * 8] = v;
    }
    __syncthreads();

    const int wave = t >> 6;                     // 0..7, wave handles 16 rows
    const int lane = t & 63;
    const int m    = lane & 15;
    const int quad = lane >> 4;

    const f16x8* wt = (const f16x8*)wtab;
    const int arow_l = wave * 16 + m;            // 0..127

    f32x4 acc0 = {0.f, 0.f, 0.f, 0.f};
    f32x4 acc1 = {0.f, 0.f, 0.f, 0.f};

    #pragma unroll
    for (int kt = 0; kt < 4; ++kt) {
        f16x8 a  = *(const f16x8*)&at[arow_l * APITCH + kt * 32 + quad * 8];
        f16x8 b0 = wt[(0 * 4 + kt) * 64 + lane];
        f16x8 b1 = wt[(1 * 4 + kt) * 64 + lane];
        acc0 = __builtin_amdgcn_mfma_f32_16x16x32_f16(a, b0, acc0, 0, 0, 0);
        acc1 = __builtin_amdgcn_mfma_f32_16x16x32_f16(a, b1, acc1, 0, 0, 0);
    }

    // C/D layout: col = lane&15, row = quad*4 + reg
    for (int i = 0; i < 4; ++i) {
        int ro = base + wave * 16 + quad * 4 + i;
        if (ro < n) {
            _Float16 h0 = (_Float16)acc0[i];
            _Float16 h1 = (_Float16)acc1[i];
            sup[(size_t)ro * OUT_FT + m]      = *(unsigned short*)&h0;
            sup[(size_t)ro * OUT_FT + 16 + m] = *(unsigned short*)&h1;
        }
    }
}

// ---- K3: bin edges into fixed-cap bucket slots (1024 thr, 16 edges/thread) --
// bucket = row>>7 (782 buckets). ebin[b*CAP+i] = { (col<<15)|val15, row&127 }
// (byte-identical to R12 verified form)
__global__ __launch_bounds__(BA_T) void gcn_binA(const int* __restrict__ erow,
                                                 const int* __restrict__ ecol,
                                                 const float* __restrict__ eval,
                                                 int* __restrict__ bptr,
                                                 uint2* __restrict__ ebin, int nE) {
    __shared__ int cnt[NBMAX];
    __shared__ int cur[NBMAX];
    const int t  = threadIdx.x;
    const int cb = blockIdx.x * BIN_E;
    cnt[t] = 0;                                  // BA_T == NBMAX
    __syncthreads();

    int      rr[16];
    unsigned cq[16];

    // load 16 edges/thread to registers (4 x int4, coalesced) + LDS histogram
    #pragma unroll
    for (int k = 0; k < 4; ++k) {
        int i0 = cb + (k * BA_T + t) * 4;
        if (i0 + 4 <= nE) {
            int4   r4 = *(const int4*)&erow[i0];
            int4   c4 = *(const int4*)&ecol[i0];
            float4 v4 = *(const float4*)&eval[i0];
            rr[k * 4 + 0] = r4.x; rr[k * 4 + 1] = r4.y;
            rr[k * 4 + 2] = r4.z; rr[k * 4 + 3] = r4.w;
            cq[k * 4 + 0] = ((unsigned)c4.x << 15) | (unsigned)(v4.x * 32767.f + 0.5f);
            cq[k * 4 + 1] = ((unsigned)c4.y << 15) | (unsigned)(v4.y * 32767.f + 0.5f);
            cq[k * 4 + 2] = ((unsigned)c4.z << 15) | (unsigned)(v4.z * 32767.f + 0.5f);
            cq[k * 4 + 3] = ((unsigned)c4.w << 15) | (unsigned)(v4.w * 32767.f + 0.5f);
            atomicAdd(&cnt[r4.x >> 7], 1);
            atomicAdd(&cnt[r4.y >> 7], 1);
            atomicAdd(&cnt[r4.z >> 7], 1);
            atomicAdd(&cnt[r4.w >> 7], 1);
        } else {
            #pragma unroll
            for (int j = 0; j < 4; ++j) {
                int i = i0 + j;
                rr[k * 4 + j] = -1;
                if (i < nE) {
                    int r = erow[i];
                    rr[k * 4 + j] = r;
                    cq[k * 4 + j] = ((unsigned)ecol[i] << 15)
                                  | (unsigned)(eval[i] * 32767.f + 0.5f);
                    atomicAdd(&cnt[r >> 7], 1);
                }
            }
        }
    }
    __syncthreads();

    // reserve one contiguous run per non-empty bucket
    if (cnt[t]) cur[t] = atomicAdd(&bptr[t], cnt[t]);
    __syncthreads();

    // place from registers (runs land contiguously; L2 merges lines)
    #pragma unroll
    for (int k = 0; k < 16; ++k) {
        int r = rr[k];
        if (r >= 0) {
            int b = r >> 7;
            int p = atomicAdd(&cur[b], 1);
            if (p < CAP) {                       // safety clamp (never expected)
                uint2 e;
                e.x = cq[k];
                e.y = (unsigned)(r & 127);
                ebin[(size_t)b * CAP + p] = e;
            }
        }
    }
}

// ---- K4: per-bucket sort with SINGLE ebin read (LDS-staged) + gather + relu --
// Block b owns rows [b*128, b*128+128). (byte-identical to R12 verified form)
__global__ __launch_bounds__(ACC_T) void gcn_acc(const uint2* __restrict__ ebin,
                                                 const int* __restrict__ bptr,
                                                 const unsigned* __restrict__ sup32,
                                                 float2* __restrict__ out, int n) {
    __shared__ unsigned      cvS[CAP];           // 16 KB raw (col|val)
    __shared__ unsigned char ryS[CAP];           // 4 KB raw row
    __shared__ unsigned      csr[CAP];           // 16 KB row-sorted (col|val)
    __shared__ int hist[RPB];
    __shared__ int segs[RPB];
    __shared__ int cursor[RPB];
    const int    t    = threadIdx.x;
    const int    b    = blockIdx.x;
    const int    cnt  = min(bptr[b], CAP);
    const size_t base = (size_t)b * CAP;

    if (t < RPB) hist[t] = 0;
    __syncthreads();

    // single global pass: stage to LDS + row histogram (native ds_add_u32)
    for (int i = t; i < cnt; i += ACC_T) {
        uint2 e = ebin[base + i];
        cvS[i] = e.x;
        ryS[i] = (unsigned char)e.y;
        atomicAdd(&hist[e.y], 1);
    }
    __syncthreads();

    // inclusive scan of 128 row counts (first 128 threads active)
    int v = 0;
    if (t < RPB) { v = hist[t]; segs[t] = v; }
    __syncthreads();
    for (int o = 1; o < RPB; o <<= 1) {
        int x = 0;
        if (t < RPB && t >= o) x = segs[t - o];
        __syncthreads();
        if (t < RPB) segs[t] += x;
        __syncthreads();
    }
    if (t < RPB) cursor[t] = segs[t] - v;        // exclusive start
    __syncthreads();

    // placement from LDS (ds_add_rtn_u32 cursor; p < cnt <= CAP by construction)
    for (int i = t; i < cnt; i += ACC_T) {
        int p = atomicAdd(&cursor[ryS[i]], 1);
        csr[p] = cvS[i];
    }
    __syncthreads();

    // gather: 16-lane group per row, register accumulate, direct global write
    const int g = t >> 4;                        // 32 groups
    const int j = t & 15;
    const int rbase = b * RPB;
    for (int rr = g; rr < RPB; rr += ACC_T / 16) {
        int end = segs[rr];
        int st  = end - hist[rr];
        float a0 = 0.f, a1 = 0.f;
        int e = st;
        for (; e + 2 <= end; e += 2) {           // 2-edge unroll for load ILP
            unsigned c0 = csr[e], c1 = csr[e + 1];
            H2 s0; s0.u = sup32[(c0 >> 15) * 16 + j];
            H2 s1; s1.u = sup32[(c1 >> 15) * 16 + j];
            float v0 = (float)(c0 & 0x7fffu) * (1.f / 32767.f);
            float v1 = (float)(c1 & 0x7fffu) * (1.f / 32767.f);
            a0 += v0 * (float)s0.h[0] + v1 * (float)s1.h[0];
            a1 += v0 * (float)s0.h[1] + v1 * (float)s1.h[1];
        }
        if (e < end) {
            unsigned c0 = csr[e];
            H2 s0; s0.u = sup32[(c0 >> 15) * 16 + j];
            float v0 = (float)(c0 & 0x7fffu) * (1.f / 32767.f);
            a0 += v0 * (float)s0.h[0];
            a1 += v0 * (float)s0.h[1];
        }
        int row = rbase + rr;
        if (row < n) {
            float2 o;
            o.x = fmaxf(a0, 0.f);
            o.y = fmaxf(a1, 0.f);
            out[(size_t)row * 16 + j] = o;
        }
    }
}

extern "C" void kernel_launch(void* const* d_in, const int* in_sizes, int n_in,
                              void* d_out, int out_size, void* d_ws, size_t ws_size,
                              hipStream_t stream) {
    const float* seq  = (const float*)d_in[0];
    const float* w    = (const float*)d_in[1];
    const int*   erow = (const int*)d_in[2];
    const int*   ecol = (const int*)d_in[3];
    const float* eval = (const float*)d_in[4];
    float* out = (float*)d_out;

    const int n_nodes = in_sizes[0] / IN_FT;
    const int n_edges = in_sizes[2];
    const int nB      = (n_nodes + RPB - 1) / RPB;    // 782 for N=100000 (<=1024)

    // workspace: sup n*32 u16 (6.4 MB) | ebin nB*CAP uint2 (25.6 MB)
    //          | bptr 1024 int | wtab 4096 f16
    unsigned short* sup  = (unsigned short*)d_ws;
    uint2*          ebin = (uint2*)(sup + (size_t)n_nodes * OUT_FT);
    int*            bptr = (int*)(ebin + (size_t)nB * CAP);
    _Float16*       wtab = (_Float16*)(bptr + NBMAX);

    // K1: weight table + zero bucket counters
    gcn_swz<<<1, 256, 0, stream>>>(w, wtab, bptr);

    // K2: dense projection sup = seq @ w (f16), 128-row tiles
    gcn_gemm_mfma<<<(n_nodes + 127) / 128, GT, 0, stream>>>(seq, wtab, sup, n_nodes);

    // K3: bucket binning (16 edges/thread, long runs)
    gcn_binA<<<(n_edges + BIN_E - 1) / BIN_E, BA_T, 0, stream>>>(erow, ecol, eval,
                                                                 bptr, ebin, n_edges);

    // K4: per-bucket single-read sort + register-accumulate gather + relu
    gcn_acc<<<nB, ACC_T, 0, stream>>>(ebin, bptr, (const unsigned*)sup,
                                      (float2*)out, n_nodes);
}

// Round 14
// 148.630 us; speedup vs baseline: 1.0279x; 1.0279x over previous
//
#include <hip/hip_runtime.h>
#include <hip/hip_bf16.h>
#include <hip/hip_fp16.h>

#define IN_FT  128
#define OUT_FT 32
#define APITCH 136   // f16 pitch for A tile: 272B rows, benign b128 bank pattern

#define RPB   128    // rows per bucket (bucket = row >> 7)
#define NBMAX 1024   // bucket-counter array size (782 used)
#define CAP   4096   // ebin slots per bucket (mean 2048, ~45 sigma headroom)
#define BA_T  1024   // threads for binA
#define ACC_T 512    // threads for acc
#define BIN_E 16384  // binA edges per block (16/thread)

typedef _Float16 f16x8 __attribute__((ext_vector_type(8)));
typedef __attribute__((ext_vector_type(4))) float f32x4;

union H2 { unsigned u; _Float16 h[2]; };

// ---- K1: swizzled f16 weight table (8 KB) + zero bucket counters ----
// wtab[tile][kt][lane][j] = w[kt*32 + (lane>>4)*8 + j][(lane&15) + tile*16]
__global__ __launch_bounds__(256) void gcn_swz(const float* __restrict__ w,
                                               _Float16* __restrict__ wtab,
                                               int* __restrict__ bptr) {
    int t = threadIdx.x;
    bptr[t]       = 0;
    bptr[t + 256] = 0;
    bptr[t + 512] = 0;
    bptr[t + 768] = 0;
    for (int i = t; i < 2 * 4 * 64 * 8; i += 256) {
        int j    = i & 7;
        int lane = (i >> 3) & 63;
        int kt   = (i >> 9) & 3;
        int tile = i >> 11;
        int k    = kt * 32 + (lane >> 4) * 8 + j;
        int c    = (lane & 15) + tile * 16;
        wtab[i] = (_Float16)w[k * OUT_FT + c];
    }
}

// ---- K2: sup(f16) = seq @ w via MFMA with LDS-staged coalesced A ----
// (byte-identical to R12 verified form, 64-row tile)
__global__ __launch_bounds__(256) void gcn_gemm_mfma(const float* __restrict__ seq,
                                                     const _Float16* __restrict__ wtab,
                                                     unsigned short* __restrict__ sup,
                                                     int n) {
    __shared__ __align__(16) _Float16 at[64 * APITCH];   // 17 KB
    const int t    = threadIdx.x;
    const int base = blockIdx.x * 64;

    for (int it = 0; it < 4; ++it) {
        int i     = it * 256 + t;
        int row_l = i >> 4;
        int c     = i & 15;
        int row   = base + row_l;
        f16x8 v = (f16x8)0;
        if (row < n) {
            const float4* p = (const float4*)(seq + (size_t)row * IN_FT + c * 8);
            float4 lo = p[0], hi = p[1];
            v[0] = (_Float16)lo.x; v[1] = (_Float16)lo.y;
            v[2] = (_Float16)lo.z; v[3] = (_Float16)lo.w;
            v[4] = (_Float16)hi.x; v[5] = (_Float16)hi.y;
            v[6] = (_Float16)hi.z; v[7] = (_Float16)hi.w;
        }
        *(f16x8*)&at[row_l * APITCH + c * 8] = v;
    }
    __syncthreads();

    const int wave = t >> 6;
    const int lane = t & 63;
    const int m    = lane & 15;
    const int quad = lane >> 4;

    const f16x8* wt = (const f16x8*)wtab;
    const int arow_l = wave * 16 + m;

    f32x4 acc0 = {0.f, 0.f, 0.f, 0.f};
    f32x4 acc1 = {0.f, 0.f, 0.f, 0.f};

    for (int kt = 0; kt < 4; ++kt) {
        f16x8 a  = *(const f16x8*)&at[arow_l * APITCH + kt * 32 + quad * 8];
        f16x8 b0 = wt[(0 * 4 + kt) * 64 + lane];
        f16x8 b1 = wt[(1 * 4 + kt) * 64 + lane];
        acc0 = __builtin_amdgcn_mfma_f32_16x16x32_f16(a, b0, acc0, 0, 0, 0);
        acc1 = __builtin_amdgcn_mfma_f32_16x16x32_f16(a, b1, acc1, 0, 0, 0);
    }

    // C/D layout: col = lane&15, row = quad*4 + reg
    for (int i = 0; i < 4; ++i) {
        int ro = base + wave * 16 + quad * 4 + i;
        if (ro < n) {
            _Float16 h0 = (_Float16)acc0[i];
            _Float16 h1 = (_Float16)acc1[i];
            sup[(size_t)ro * OUT_FT + m]      = *(unsigned short*)&h0;
            sup[(size_t)ro * OUT_FT + 16 + m] = *(unsigned short*)&h1;
        }
    }
}

// ---- K3: bin edges into fixed-cap bucket slots (1024 thr, 16 edges/thread) --
// bucket = row>>7 (782 buckets). ebin[b*CAP+i] = { (col<<15)|val15, row&127 }
// (byte-identical to R12 verified form)
__global__ __launch_bounds__(BA_T) void gcn_binA(const int* __restrict__ erow,
                                                 const int* __restrict__ ecol,
                                                 const float* __restrict__ eval,
                                                 int* __restrict__ bptr,
                                                 uint2* __restrict__ ebin, int nE) {
    __shared__ int cnt[NBMAX];
    __shared__ int cur[NBMAX];
    const int t  = threadIdx.x;
    const int cb = blockIdx.x * BIN_E;
    cnt[t] = 0;                                  // BA_T == NBMAX
    __syncthreads();

    int      rr[16];
    unsigned cq[16];

    // load 16 edges/thread to registers (4 x int4, coalesced) + LDS histogram
    #pragma unroll
    for (int k = 0; k < 4; ++k) {
        int i0 = cb + (k * BA_T + t) * 4;
        if (i0 + 4 <= nE) {
            int4   r4 = *(const int4*)&erow[i0];
            int4   c4 = *(const int4*)&ecol[i0];
            float4 v4 = *(const float4*)&eval[i0];
            rr[k * 4 + 0] = r4.x; rr[k * 4 + 1] = r4.y;
            rr[k * 4 + 2] = r4.z; rr[k * 4 + 3] = r4.w;
            cq[k * 4 + 0] = ((unsigned)c4.x << 15) | (unsigned)(v4.x * 32767.f + 0.5f);
            cq[k * 4 + 1] = ((unsigned)c4.y << 15) | (unsigned)(v4.y * 32767.f + 0.5f);
            cq[k * 4 + 2] = ((unsigned)c4.z << 15) | (unsigned)(v4.z * 32767.f + 0.5f);
            cq[k * 4 + 3] = ((unsigned)c4.w << 15) | (unsigned)(v4.w * 32767.f + 0.5f);
            atomicAdd(&cnt[r4.x >> 7], 1);
            atomicAdd(&cnt[r4.y >> 7], 1);
            atomicAdd(&cnt[r4.z >> 7], 1);
            atomicAdd(&cnt[r4.w >> 7], 1);
        } else {
            #pragma unroll
            for (int j = 0; j < 4; ++j) {
                int i = i0 + j;
                rr[k * 4 + j] = -1;
                if (i < nE) {
                    int r = erow[i];
                    rr[k * 4 + j] = r;
                    cq[k * 4 + j] = ((unsigned)ecol[i] << 15)
                                  | (unsigned)(eval[i] * 32767.f + 0.5f);
                    atomicAdd(&cnt[r >> 7], 1);
                }
            }
        }
    }
    __syncthreads();

    // reserve one contiguous run per non-empty bucket
    if (cnt[t]) cur[t] = atomicAdd(&bptr[t], cnt[t]);
    __syncthreads();

    // place from registers (runs land contiguously; L2 merges lines)
    #pragma unroll
    for (int k = 0; k < 16; ++k) {
        int r = rr[k];
        if (r >= 0) {
            int b = r >> 7;
            int p = atomicAdd(&cur[b], 1);
            if (p < CAP) {                       // safety clamp (never expected)
                uint2 e;
                e.x = cq[k];
                e.y = (unsigned)(r & 127);
                ebin[(size_t)b * CAP + p] = e;
            }
        }
    }
}

// ---- K4: per-bucket single-read sort + 8-lane register-accum gather + relu --
// Block b owns rows [b*128, b*128+128). Gather uses 8 lanes/row with uint2
// sup loads: halves (edge x lane) issue units vs 16-lane form, same traffic.
__global__ __launch_bounds__(ACC_T) void gcn_acc(const uint2* __restrict__ ebin,
                                                 const int* __restrict__ bptr,
                                                 const unsigned* __restrict__ sup32,
                                                 float* __restrict__ out, int n) {
    __shared__ unsigned      cvS[CAP];           // 16 KB raw (col|val)
    __shared__ unsigned char ryS[CAP];           // 4 KB raw row
    __shared__ unsigned      csr[CAP];           // 16 KB row-sorted (col|val)
    __shared__ int hist[RPB];
    __shared__ int segs[RPB];
    __shared__ int cursor[RPB];
    const int    t    = threadIdx.x;
    const int    b    = blockIdx.x;
    const int    cnt  = min(bptr[b], CAP);
    const size_t base = (size_t)b * CAP;

    if (t < RPB) hist[t] = 0;
    __syncthreads();

    // single global pass: stage to LDS + row histogram (native ds_add_u32)
    for (int i = t; i < cnt; i += ACC_T) {
        uint2 e = ebin[base + i];
        cvS[i] = e.x;
        ryS[i] = (unsigned char)e.y;
        atomicAdd(&hist[e.y], 1);
    }
    __syncthreads();

    // inclusive scan of 128 row counts (first 128 threads active)
    int v = 0;
    if (t < RPB) { v = hist[t]; segs[t] = v; }
    __syncthreads();
    for (int o = 1; o < RPB; o <<= 1) {
        int x = 0;
        if (t < RPB && t >= o) x = segs[t - o];
        __syncthreads();
        if (t < RPB) segs[t] += x;
        __syncthreads();
    }
    if (t < RPB) cursor[t] = segs[t] - v;        // exclusive start
    __syncthreads();

    // placement from LDS (ds_add_rtn_u32 cursor; p < cnt <= CAP by construction)
    for (int i = t; i < cnt; i += ACC_T) {
        int p = atomicAdd(&cursor[ryS[i]], 1);
        csr[p] = cvS[i];
    }
    __syncthreads();

    // gather: 8-lane group per row, lane j owns cols 4j..4j+3 (uint2 sup load)
    const int g = t >> 3;                        // 64 groups
    const int j = t & 7;
    const int rbase = b * RPB;
    const uint2* sup2 = (const uint2*)sup32;
    for (int rr = g; rr < RPB; rr += ACC_T / 8) {
        int end = segs[rr];
        int st  = end - hist[rr];
        float a0 = 0.f, a1 = 0.f, a2 = 0.f, a3 = 0.f;
        int e = st;
        for (; e + 2 <= end; e += 2) {           // 2-edge unroll for load ILP
            unsigned c0 = csr[e], c1 = csr[e + 1];
            uint2 s0 = sup2[(c0 >> 15) * 8 + j];
            uint2 s1 = sup2[(c1 >> 15) * 8 + j];
            float v0 = (float)(c0 & 0x7fffu) * (1.f / 32767.f);
            float v1 = (float)(c1 & 0x7fffu) * (1.f / 32767.f);
            H2 x0, y0, x1, y1;
            x0.u = s0.x; y0.u = s0.y; x1.u = s1.x; y1.u = s1.y;
            a0 += v0 * (float)x0.h[0] + v1 * (float)x1.h[0];
            a1 += v0 * (float)x0.h[1] + v1 * (float)x1.h[1];
            a2 += v0 * (float)y0.h[0] + v1 * (float)y1.h[0];
            a3 += v0 * (float)y0.h[1] + v1 * (float)y1.h[1];
        }
        if (e < end) {
            unsigned c0 = csr[e];
            uint2 s0 = sup2[(c0 >> 15) * 8 + j];
            float v0 = (float)(c0 & 0x7fffu) * (1.f / 32767.f);
            H2 x0, y0;
            x0.u = s0.x; y0.u = s0.y;
            a0 += v0 * (float)x0.h[0];
            a1 += v0 * (float)x0.h[1];
            a2 += v0 * (float)y0.h[0];
            a3 += v0 * (float)y0.h[1];
        }
        int row = rbase + rr;
        if (row < n) {
            float4 o;
            o.x = fmaxf(a0, 0.f);
            o.y = fmaxf(a1, 0.f);
            o.z = fmaxf(a2, 0.f);
            o.w = fmaxf(a3, 0.f);
            ((float4*)out)[(size_t)row * 8 + j] = o;
        }
    }
}

extern "C" void kernel_launch(void* const* d_in, const int* in_sizes, int n_in,
                              void* d_out, int out_size, void* d_ws, size_t ws_size,
                              hipStream_t stream) {
    const float* seq  = (const float*)d_in[0];
    const float* w    = (const float*)d_in[1];
    const int*   erow = (const int*)d_in[2];
    const int*   ecol = (const int*)d_in[3];
    const float* eval = (const float*)d_in[4];
    float* out = (float*)d_out;

    const int n_nodes = in_sizes[0] / IN_FT;
    const int n_edges = in_sizes[2];
    const int nB      = (n_nodes + RPB - 1) / RPB;    // 782 for N=100000 (<=1024)

    // workspace: sup n*32 u16 (6.4 MB) | ebin nB*CAP uint2 (25.6 MB)
    //          | bptr 1024 int | wtab 4096 f16
    unsigned short* sup  = (unsigned short*)d_ws;
    uint2*          ebin = (uint2*)(sup + (size_t)n_nodes * OUT_FT);
    int*            bptr = (int*)(ebin + (size_t)nB * CAP);
    _Float16*       wtab = (_Float16*)(bptr + NBMAX);

    // K1: weight table + zero bucket counters
    gcn_swz<<<1, 256, 0, stream>>>(w, wtab, bptr);

    // K2: dense projection sup = seq @ w (f16)
    gcn_gemm_mfma<<<(n_nodes + 63) / 64, 256, 0, stream>>>(seq, wtab, sup, n_nodes);

    // K3: bucket binning (16 edges/thread, long runs)
    gcn_binA<<<(n_edges + BIN_E - 1) / BIN_E, BA_T, 0, stream>>>(erow, ecol, eval,
                                                                 bptr, ebin, n_edges);

    // K4: per-bucket single-read sort + 8-lane register-accumulate gather + relu
    gcn_acc<<<nB, ACC_T, 0, stream>>>(ebin, bptr, (const unsigned*)sup,
                                      out, n_nodes);
}

// Round 15
// 146.079 us; speedup vs baseline: 1.0459x; 1.0175x over previous
//
#include <hip/hip_runtime.h>
#include <hip/hip_bf16.h>
#include <hip/hip_fp16.h>

#define IN_FT  128
#define OUT_FT 32
#define APITCH 136   // f16 pitch for A tile: 272B rows, benign b128 bank pattern

#define RPB   128    // rows per bucket (bucket = row >> 7)
#define NBMAX 1024   // bucket-counter array size (782 used)
#define CAP   4096   // ebin slots per bucket (mean 2048, ~45 sigma headroom)
#define BA_T  1024   // threads for binA
#define ACC_T 512    // threads for acc
#define BIN_E 8192   // binA edges per block (8/thread; 196 blocks -> 77% CU cover)

typedef _Float16 f16x8 __attribute__((ext_vector_type(8)));
typedef __attribute__((ext_vector_type(4))) float f32x4;

union H2 { unsigned u; _Float16 h[2]; };

// ---- K1: swizzled f16 weight table (8 KB) + zero bucket counters ----
// wtab[tile][kt][lane][j] = w[kt*32 + (lane>>4)*8 + j][(lane&15) + tile*16]
__global__ __launch_bounds__(256) void gcn_swz(const float* __restrict__ w,
                                               _Float16* __restrict__ wtab,
                                               int* __restrict__ bptr) {
    int t = threadIdx.x;
    bptr[t]       = 0;
    bptr[t + 256] = 0;
    bptr[t + 512] = 0;
    bptr[t + 768] = 0;
    for (int i = t; i < 2 * 4 * 64 * 8; i += 256) {
        int j    = i & 7;
        int lane = (i >> 3) & 63;
        int kt   = (i >> 9) & 3;
        int tile = i >> 11;
        int k    = kt * 32 + (lane >> 4) * 8 + j;
        int c    = (lane & 15) + tile * 16;
        wtab[i] = (_Float16)w[k * OUT_FT + c];
    }
}

// ---- K2: sup(f16) = seq @ w via MFMA with LDS-staged coalesced A ----
// (byte-identical to R14 verified form, 64-row tile)
__global__ __launch_bounds__(256) void gcn_gemm_mfma(const float* __restrict__ seq,
                                                     const _Float16* __restrict__ wtab,
                                                     unsigned short* __restrict__ sup,
                                                     int n) {
    __shared__ __align__(16) _Float16 at[64 * APITCH];   // 17 KB
    const int t    = threadIdx.x;
    const int base = blockIdx.x * 64;

    for (int it = 0; it < 4; ++it) {
        int i     = it * 256 + t;
        int row_l = i >> 4;
        int c     = i & 15;
        int row   = base + row_l;
        f16x8 v = (f16x8)0;
        if (row < n) {
            const float4* p = (const float4*)(seq + (size_t)row * IN_FT + c * 8);
            float4 lo = p[0], hi = p[1];
            v[0] = (_Float16)lo.x; v[1] = (_Float16)lo.y;
            v[2] = (_Float16)lo.z; v[3] = (_Float16)lo.w;
            v[4] = (_Float16)hi.x; v[5] = (_Float16)hi.y;
            v[6] = (_Float16)hi.z; v[7] = (_Float16)hi.w;
        }
        *(f16x8*)&at[row_l * APITCH + c * 8] = v;
    }
    __syncthreads();

    const int wave = t >> 6;
    const int lane = t & 63;
    const int m    = lane & 15;
    const int quad = lane >> 4;

    const f16x8* wt = (const f16x8*)wtab;
    const int arow_l = wave * 16 + m;

    f32x4 acc0 = {0.f, 0.f, 0.f, 0.f};
    f32x4 acc1 = {0.f, 0.f, 0.f, 0.f};

    for (int kt = 0; kt < 4; ++kt) {
        f16x8 a  = *(const f16x8*)&at[arow_l * APITCH + kt * 32 + quad * 8];
        f16x8 b0 = wt[(0 * 4 + kt) * 64 + lane];
        f16x8 b1 = wt[(1 * 4 + kt) * 64 + lane];
        acc0 = __builtin_amdgcn_mfma_f32_16x16x32_f16(a, b0, acc0, 0, 0, 0);
        acc1 = __builtin_amdgcn_mfma_f32_16x16x32_f16(a, b1, acc1, 0, 0, 0);
    }

    // C/D layout: col = lane&15, row = quad*4 + reg
    for (int i = 0; i < 4; ++i) {
        int ro = base + wave * 16 + quad * 4 + i;
        if (ro < n) {
            _Float16 h0 = (_Float16)acc0[i];
            _Float16 h1 = (_Float16)acc1[i];
            sup[(size_t)ro * OUT_FT + m]      = *(unsigned short*)&h0;
            sup[(size_t)ro * OUT_FT + 16 + m] = *(unsigned short*)&h1;
        }
    }
}

// ---- K3: bin edges into fixed-cap bucket slots (1024 thr, 8 edges/thread) ---
// bucket = row>>7 (782 buckets). 196 blocks: 16 waves/CU depth kept, active-CU
// count doubled vs 16-edge form. ebin[b*CAP+i] = { (col<<15)|val15, row&127 }
__global__ __launch_bounds__(BA_T) void gcn_binA(const int* __restrict__ erow,
                                                 const int* __restrict__ ecol,
                                                 const float* __restrict__ eval,
                                                 int* __restrict__ bptr,
                                                 uint2* __restrict__ ebin, int nE) {
    __shared__ int cnt[NBMAX];
    __shared__ int cur[NBMAX];
    const int t  = threadIdx.x;
    const int cb = blockIdx.x * BIN_E;
    cnt[t] = 0;                                  // BA_T == NBMAX
    __syncthreads();

    int      rr[8];
    unsigned cq[8];

    // load 8 edges/thread to registers (2 x int4, coalesced) + LDS histogram
    #pragma unroll
    for (int k = 0; k < 2; ++k) {
        int i0 = cb + (k * BA_T + t) * 4;
        if (i0 + 4 <= nE) {
            int4   r4 = *(const int4*)&erow[i0];
            int4   c4 = *(const int4*)&ecol[i0];
            float4 v4 = *(const float4*)&eval[i0];
            rr[k * 4 + 0] = r4.x; rr[k * 4 + 1] = r4.y;
            rr[k * 4 + 2] = r4.z; rr[k * 4 + 3] = r4.w;
            cq[k * 4 + 0] = ((unsigned)c4.x << 15) | (unsigned)(v4.x * 32767.f + 0.5f);
            cq[k * 4 + 1] = ((unsigned)c4.y << 15) | (unsigned)(v4.y * 32767.f + 0.5f);
            cq[k * 4 + 2] = ((unsigned)c4.z << 15) | (unsigned)(v4.z * 32767.f + 0.5f);
            cq[k * 4 + 3] = ((unsigned)c4.w << 15) | (unsigned)(v4.w * 32767.f + 0.5f);
            atomicAdd(&cnt[r4.x >> 7], 1);
            atomicAdd(&cnt[r4.y >> 7], 1);
            atomicAdd(&cnt[r4.z >> 7], 1);
            atomicAdd(&cnt[r4.w >> 7], 1);
        } else {
            #pragma unroll
            for (int j = 0; j < 4; ++j) {
                int i = i0 + j;
                rr[k * 4 + j] = -1;
                if (i < nE) {
                    int r = erow[i];
                    rr[k * 4 + j] = r;
                    cq[k * 4 + j] = ((unsigned)ecol[i] << 15)
                                  | (unsigned)(eval[i] * 32767.f + 0.5f);
                    atomicAdd(&cnt[r >> 7], 1);
                }
            }
        }
    }
    __syncthreads();

    // reserve one contiguous run per non-empty bucket
    if (cnt[t]) cur[t] = atomicAdd(&bptr[t], cnt[t]);
    __syncthreads();

    // place from registers (runs land contiguously; L2 merges lines)
    #pragma unroll
    for (int k = 0; k < 8; ++k) {
        int r = rr[k];
        if (r >= 0) {
            int b = r >> 7;
            int p = atomicAdd(&cur[b], 1);
            if (p < CAP) {                       // safety clamp (never expected)
                uint2 e;
                e.x = cq[k];
                e.y = (unsigned)(r & 127);
                ebin[(size_t)b * CAP + p] = e;
            }
        }
    }
}

// ---- K4: per-bucket single-read sort + 8-lane register-accum gather + relu --
// (byte-identical to R14 verified form)
__global__ __launch_bounds__(ACC_T) void gcn_acc(const uint2* __restrict__ ebin,
                                                 const int* __restrict__ bptr,
                                                 const unsigned* __restrict__ sup32,
                                                 float* __restrict__ out, int n) {
    __shared__ unsigned      cvS[CAP];           // 16 KB raw (col|val)
    __shared__ unsigned char ryS[CAP];           // 4 KB raw row
    __shared__ unsigned      csr[CAP];           // 16 KB row-sorted (col|val)
    __shared__ int hist[RPB];
    __shared__ int segs[RPB];
    __shared__ int cursor[RPB];
    const int    t    = threadIdx.x;
    const int    b    = blockIdx.x;
    const int    cnt  = min(bptr[b], CAP);
    const size_t base = (size_t)b * CAP;

    if (t < RPB) hist[t] = 0;
    __syncthreads();

    // single global pass: stage to LDS + row histogram (native ds_add_u32)
    for (int i = t; i < cnt; i += ACC_T) {
        uint2 e = ebin[base + i];
        cvS[i] = e.x;
        ryS[i] = (unsigned char)e.y;
        atomicAdd(&hist[e.y], 1);
    }
    __syncthreads();

    // inclusive scan of 128 row counts (first 128 threads active)
    int v = 0;
    if (t < RPB) { v = hist[t]; segs[t] = v; }
    __syncthreads();
    for (int o = 1; o < RPB; o <<= 1) {
        int x = 0;
        if (t < RPB && t >= o) x = segs[t - o];
        __syncthreads();
        if (t < RPB) segs[t] += x;
        __syncthreads();
    }
    if (t < RPB) cursor[t] = segs[t] - v;        // exclusive start
    __syncthreads();

    // placement from LDS (ds_add_rtn_u32 cursor; p < cnt <= CAP by construction)
    for (int i = t; i < cnt; i += ACC_T) {
        int p = atomicAdd(&cursor[ryS[i]], 1);
        csr[p] = cvS[i];
    }
    __syncthreads();

    // gather: 8-lane group per row, lane j owns cols 4j..4j+3 (uint2 sup load)
    const int g = t >> 3;                        // 64 groups
    const int j = t & 7;
    const int rbase = b * RPB;
    const uint2* sup2 = (const uint2*)sup32;
    for (int rr = g; rr < RPB; rr += ACC_T / 8) {
        int end = segs[rr];
        int st  = end - hist[rr];
        float a0 = 0.f, a1 = 0.f, a2 = 0.f, a3 = 0.f;
        int e = st;
        for (; e + 2 <= end; e += 2) {           // 2-edge unroll for load ILP
            unsigned c0 = csr[e], c1 = csr[e + 1];
            uint2 s0 = sup2[(c0 >> 15) * 8 + j];
            uint2 s1 = sup2[(c1 >> 15) * 8 + j];
            float v0 = (float)(c0 & 0x7fffu) * (1.f / 32767.f);
            float v1 = (float)(c1 & 0x7fffu) * (1.f / 32767.f);
            H2 x0, y0, x1, y1;
            x0.u = s0.x; y0.u = s0.y; x1.u = s1.x; y1.u = s1.y;
            a0 += v0 * (float)x0.h[0] + v1 * (float)x1.h[0];
            a1 += v0 * (float)x0.h[1] + v1 * (float)x1.h[1];
            a2 += v0 * (float)y0.h[0] + v1 * (float)y1.h[0];
            a3 += v0 * (float)y0.h[1] + v1 * (float)y1.h[1];
        }
        if (e < end) {
            unsigned c0 = csr[e];
            uint2 s0 = sup2[(c0 >> 15) * 8 + j];
            float v0 = (float)(c0 & 0x7fffu) * (1.f / 32767.f);
            H2 x0, y0;
            x0.u = s0.x; y0.u = s0.y;
            a0 += v0 * (float)x0.h[0];
            a1 += v0 * (float)x0.h[1];
            a2 += v0 * (float)y0.h[0];
            a3 += v0 * (float)y0.h[1];
        }
        int row = rbase + rr;
        if (row < n) {
            float4 o;
            o.x = fmaxf(a0, 0.f);
            o.y = fmaxf(a1, 0.f);
            o.z = fmaxf(a2, 0.f);
            o.w = fmaxf(a3, 0.f);
            ((float4*)out)[(size_t)row * 8 + j] = o;
        }
    }
}

extern "C" void kernel_launch(void* const* d_in, const int* in_sizes, int n_in,
                              void* d_out, int out_size, void* d_ws, size_t ws_size,
                              hipStream_t stream) {
    const float* seq  = (const float*)d_in[0];
    const float* w    = (const float*)d_in[1];
    const int*   erow = (const int*)d_in[2];
    const int*   ecol = (const int*)d_in[3];
    const float* eval = (const float*)d_in[4];
    float* out = (float*)d_out;

    const int n_nodes = in_sizes[0] / IN_FT;
    const int n_edges = in_sizes[2];
    const int nB      = (n_nodes + RPB - 1) / RPB;    // 782 for N=100000 (<=1024)

    // workspace: sup n*32 u16 (6.4 MB) | ebin nB*CAP uint2 (25.6 MB)
    //          | bptr 1024 int | wtab 4096 f16
    unsigned short* sup  = (unsigned short*)d_ws;
    uint2*          ebin = (uint2*)(sup + (size_t)n_nodes * OUT_FT);
    int*            bptr = (int*)(ebin + (size_t)nB * CAP);
    _Float16*       wtab = (_Float16*)(bptr + NBMAX);

    // K1: weight table + zero bucket counters
    gcn_swz<<<1, 256, 0, stream>>>(w, wtab, bptr);

    // K2: dense projection sup = seq @ w (f16)
    gcn_gemm_mfma<<<(n_nodes + 63) / 64, 256, 0, stream>>>(seq, wtab, sup, n_nodes);

    // K3: bucket binning (8 edges/thread, 196 blocks)
    gcn_binA<<<(n_edges + BIN_E - 1) / BIN_E, BA_T, 0, stream>>>(erow, ecol, eval,
                                                                 bptr, ebin, n_edges);

    // K4: per-bucket single-read sort + 8-lane register-accumulate gather + relu
    gcn_acc<<<nB, ACC_T, 0, stream>>>(ebin, bptr, (const unsigned*)sup,
                                      out, n_nodes);
}